// Round 6
// baseline (361.140 us; speedup 1.0000x reference)
//
#include <hip/hip_runtime.h>

#define L_SEQ 2048
#define DMODEL 1024
#define DINNER 2048
#define NCHUNK 64
#define TCHUNK 32

typedef __attribute__((ext_vector_type(8))) short bf16x8;
typedef __attribute__((ext_vector_type(4))) float f32x4;

__device__ __forceinline__ float bf2f(unsigned short u) {
  return __uint_as_float(((unsigned)u) << 16);
}
__device__ __forceinline__ unsigned short f2bf(float f) {
  unsigned u = __float_as_uint(f);
  return (unsigned short)((u + 0x7FFFu + ((u >> 16) & 1u)) >> 16);
}
__device__ __forceinline__ void gload_lds16(const void* g, void* l) {
  __builtin_amdgcn_global_load_lds(
      (const __attribute__((address_space(1))) void*)g,
      (__attribute__((address_space(3))) void*)l, 16, 0, 0);
}

// ---------------- fp32 -> bf16 convert (vectorized) ----------------
__global__ void cvt_f32_bf16(const float4* __restrict__ in, ushort4* __restrict__ out, int n4) {
  int i = blockIdx.x * blockDim.x + threadIdx.x;
  if (i >= n4) return;
  float4 v = in[i];
  ushort4 o;
  o.x = f2bf(v.x); o.y = f2bf(v.y); o.z = f2bf(v.z); o.w = f2bf(v.w);
  out[i] = o;
}

__global__ void zero_bf16(ushort4* __restrict__ out, int n4) {
  int i = blockIdx.x * blockDim.x + threadIdx.x;
  if (i >= n4) return;
  out[i] = ushort4{0, 0, 0, 0};
}

// ---------------- bf16 GEMM, C = A[M,K] * B[N,K]^T ----------------
// 128x128 tile, BK=64, 4 LDS buffers, depth-3 prefetch with counted vmcnt (T3+T4),
// source-side XOR swizzle (T2, rule #21), XCD chunk swizzle (T1). ksplit in {1,2}.
// EPI: 0 = store bf16
//      3 = col<2048: softplus(v+aux[col]) -> bf16 outb; 2048<=col<2080: v -> outf[row*32+col-2048]
//      4 = partial f32 store at outf[ks*M*N + row*N + col]
template <int EPI>
__global__ __launch_bounds__(256) void gemm_bk64(
    const unsigned short* __restrict__ A, const unsigned short* __restrict__ B,
    int M, int N, int K, int nx, int ksplit,
    float* __restrict__ outf, unsigned short* __restrict__ outb,
    const float* __restrict__ aux) {
  __shared__ __align__(16) unsigned short As[4 * 128 * 64];  // 64 KB
  __shared__ __align__(16) unsigned short Bs[4 * 128 * 64];  // 64 KB
  const int tid = threadIdx.x;
  const int lane = tid & 63;
  const int wave = tid >> 6;
  const int wm = wave >> 1, wn = wave & 1;

  // XCD-aware bijective chunk swizzle (nwg % 8 == 0)
  const int nwg = gridDim.x;
  const int wg = blockIdx.x;
  const int swzb = (wg & 7) * (nwg >> 3) + (wg >> 3);
  const int tiles = nwg / ksplit;
  const int ks = swzb / tiles;
  const int t = swzb - ks * tiles;
  const int bx = t % nx, by = t / nx;
  const int bm = by * 128, bn = bx * 128;
  const int Ks = K / ksplit;
  const int kbeg = ks * Ks;
  const int nst = Ks >> 6;  // BK=64 stages

  // Staging map: per instruction q (0..3): row = q*32 + wave*8 + (lane>>3), slot = lane&7.
  // LDS dest is LINEAR (lane*16B); global source slot is XOR-swizzled: slot' = slot ^ (row&7).
  // (row&7) == (lane>>3)&7 independent of q/wave.
  const int srow = wave * 8 + (lane >> 3);
  const int swslot = (lane & 7) ^ ((lane >> 3) & 7);
  const unsigned short* Ag = A + (size_t)(bm + srow) * K + kbeg + swslot * 8;
  const unsigned short* Bg = B + (size_t)(bn + srow) * K + kbeg + swslot * 8;

  auto STAGE = [&](int buf, int kof) {
#pragma unroll
    for (int q = 0; q < 4; ++q) {
      gload_lds16(Ag + (size_t)q * 32 * K + kof, &As[buf * 8192 + (q * 32 + wave * 8) * 64]);
      gload_lds16(Bg + (size_t)q * 32 * K + kof, &Bs[buf * 8192 + (q * 32 + wave * 8) * 64]);
    }
  };

  f32x4 acc[4][4] = {};

  const int g = lane >> 4;
  const int r16 = lane & 15;
  const int rsw = r16 & 7;

  STAGE(0, 0);
  STAGE(1, 64);
  STAGE(2, 128);
  int cur = 0, stg = 3;

  for (int i = 0; i < nst; ++i) {
    int rem = nst - 1 - i;
    if (rem >= 2) {
      asm volatile("s_waitcnt vmcnt(16)" ::: "memory");
    } else if (rem == 1) {
      asm volatile("s_waitcnt vmcnt(8)" ::: "memory");
    } else {
      asm volatile("s_waitcnt vmcnt(0)" ::: "memory");
    }
    __builtin_amdgcn_s_barrier();
    asm volatile("" ::: "memory");
    if (i + 3 < nst) {
      STAGE(stg, (i + 3) * 64);
      stg = (stg + 1) & 3;
    }

#pragma unroll
    for (int kk = 0; kk < 2; ++kk) {
      bf16x8 a[4], b[4];
#pragma unroll
      for (int ii = 0; ii < 4; ++ii)
        a[ii] = *(const bf16x8*)&As[cur * 8192 + (wm * 64 + ii * 16 + r16) * 64 +
                                    ((kk * 4 + g) ^ rsw) * 8];
#pragma unroll
      for (int j = 0; j < 4; ++j)
        b[j] = *(const bf16x8*)&Bs[cur * 8192 + (wn * 64 + j * 16 + r16) * 64 +
                                   ((kk * 4 + g) ^ rsw) * 8];
#pragma unroll
      for (int ii = 0; ii < 4; ++ii)
#pragma unroll
        for (int j = 0; j < 4; ++j)
          acc[ii][j] = __builtin_amdgcn_mfma_f32_16x16x32_bf16(a[ii], b[j], acc[ii][j], 0, 0, 0);
    }

    cur = (cur + 1) & 3;
  }

  const int rq = lane >> 4;
#pragma unroll
  for (int i = 0; i < 4; ++i)
#pragma unroll
    for (int j = 0; j < 4; ++j)
#pragma unroll
      for (int r = 0; r < 4; ++r) {
        int row = bm + wm * 64 + i * 16 + rq * 4 + r;
        int col = bn + wn * 64 + j * 16 + r16;
        float v = acc[i][j][r];
        if (EPI == 0) {
          outb[(size_t)row * N + col] = f2bf(v);
        } else if (EPI == 3) {
          if (col < 2048) {
            float tt = v + aux[col];
            float sp = (tt > 15.f) ? tt : log1pf(__expf(tt));
            outb[(size_t)row * 2048 + col] = f2bf(sp);
          } else if (col < 2080) {
            outf[(size_t)row * 32 + (col - 2048)] = v;
          }
        } else {  // EPI == 4: split-K partial
          outf[(size_t)ks * M * N + (size_t)row * N + col] = v;
        }
      }
}

// ---------------- split-K reduce + residual add ----------------
__global__ void reduce_addx(const float4* __restrict__ p, const float4* __restrict__ x,
                            float4* __restrict__ out, int n4) {
  int i = blockIdx.x * 256 + threadIdx.x;
  if (i >= n4) return;
  float4 a = p[i], b = p[n4 + i], c = x[i];
  float4 o;
  o.x = a.x + b.x + c.x; o.y = a.y + b.y + c.y;
  o.z = a.z + b.z + c.z; o.w = a.w + b.w + c.w;
  out[i] = o;
}

// ---------------- causal depthwise conv (D_CONV=4) + SiLU; also silu(z) ----------------
__global__ __launch_bounds__(256) void conv_silu8(
    const unsigned short* __restrict__ xz,
    const float* __restrict__ cw, const float* __restrict__ cb,
    unsigned short* __restrict__ x_ssm, unsigned short* __restrict__ sz_out) {
  int idx = blockIdx.x * 256 + threadIdx.x;  // 2048 l * 256 cgroups
  int l = idx >> 8, c0 = (idx & 255) * 8;
  float acc[8];
  float4 b0 = *(const float4*)(cb + c0);
  float4 b1 = *(const float4*)(cb + c0 + 4);
  acc[0] = b0.x; acc[1] = b0.y; acc[2] = b0.z; acc[3] = b0.w;
  acc[4] = b1.x; acc[5] = b1.y; acc[6] = b1.z; acc[7] = b1.w;
  float4 w[8];
#pragma unroll
  for (int j = 0; j < 8; ++j) w[j] = *(const float4*)(cw + (c0 + j) * 4);
#pragma unroll
  for (int k = 0; k < 4; ++k) {
    int lt = l - 3 + k;
    if (lt >= 0) {
      bf16x8 v = *(const bf16x8*)(xz + (size_t)lt * 4096 + c0);
      const float* wk = (const float*)w;
#pragma unroll
      for (int j = 0; j < 8; ++j)
        acc[j] = fmaf(bf2f((unsigned short)v[j]), wk[j * 4 + k], acc[j]);
    }
  }
  bf16x8 zr = *(const bf16x8*)(xz + (size_t)l * 4096 + 2048 + c0);
  bf16x8 ox, oz;
#pragma unroll
  for (int j = 0; j < 8; ++j) {
    float a = acc[j];
    ox[j] = (short)f2bf(a / (1.f + __expf(-a)));
    float zv = bf2f((unsigned short)zr[j]);
    oz[j] = (short)f2bf(zv / (1.f + __expf(-zv)));
  }
  *(bf16x8*)(x_ssm + (size_t)idx * 8) = ox;
  *(bf16x8*)(sz_out + (size_t)idx * 8) = oz;
}

// ---------------- chunked parallel scan, thread-per-channel (16 states in regs) ----------
__global__ __launch_bounds__(256) void scan_passA(
    const unsigned short* __restrict__ dtb, const unsigned short* __restrict__ x_ssm,
    const float* __restrict__ x_dbl, const float* __restrict__ A_log,
    float* __restrict__ Pout, float* __restrict__ Hout) {
  int tid = threadIdx.x;
  int c = blockIdx.x & (NCHUNK - 1), db = blockIdx.x / NCHUNK;
  int d = db * 256 + tid;
  int t0 = c * TCHUNK;
  float Av[16];
  const float4* al4 = (const float4*)(A_log + d * 16);
#pragma unroll
  for (int q = 0; q < 4; ++q) {
    float4 a = al4[q];
    Av[q * 4 + 0] = -__expf(a.x); Av[q * 4 + 1] = -__expf(a.y);
    Av[q * 4 + 2] = -__expf(a.z); Av[q * 4 + 3] = -__expf(a.w);
  }
  float h[16];
#pragma unroll
  for (int s = 0; s < 16; ++s) h[s] = 0.f;
  float sum_dt = 0.f;
#pragma unroll 2
  for (int i = 0; i < TCHUNK; ++i) {
    int t = t0 + i;
    float dtv = bf2f(dtb[(size_t)t * 2048 + d]);
    float xv = bf2f(x_ssm[(size_t)t * 2048 + d]);
    float dtx = dtv * xv;
    sum_dt += dtv;
    const float* B = x_dbl + t * 32;  // wave-uniform -> scalar loads
#pragma unroll
    for (int s = 0; s < 16; ++s) {
      float dA = __expf(dtv * Av[s]);
      h[s] = fmaf(dA, h[s], B[s] * dtx);
    }
  }
  float* Ho = Hout + (size_t)c * 32768 + d * 16;
  float* Po = Pout + (size_t)c * 32768 + d * 16;
#pragma unroll
  for (int s = 0; s < 16; ++s) Ho[s] = h[s];
#pragma unroll
  for (int s = 0; s < 16; ++s) Po[s] = __expf(sum_dt * Av[s]);
}

// Pass B: serial combine; rewrites P buffer in-place with chunk-entry states (Hinit).
__global__ __launch_bounds__(256) void scan_passB(
    float* __restrict__ P, const float* __restrict__ Hloc) {
  int i = blockIdx.x * 256 + threadIdx.x;  // 32768 (d,s)
  float h = 0.f;
  for (int c = 0; c < NCHUNK; ++c) {
    size_t o = (size_t)c * 32768 + i;
    float p = P[o];
    float hl = Hloc[o];
    P[o] = h;
    h = fmaf(p, h, hl);
  }
}

// Pass C: re-run chunk from entry state; emit gated y (bf16).
__global__ __launch_bounds__(256) void scan_passC(
    const unsigned short* __restrict__ dtb, const unsigned short* __restrict__ x_ssm,
    const float* __restrict__ x_dbl, const float* __restrict__ A_log,
    const float* __restrict__ D_param, const unsigned short* __restrict__ silu_z,
    const float* __restrict__ Hinit, unsigned short* __restrict__ y_out) {
  int tid = threadIdx.x;
  int c = blockIdx.x & (NCHUNK - 1), db = blockIdx.x / NCHUNK;
  int d = db * 256 + tid;
  int t0 = c * TCHUNK;
  float Av[16];
  const float4* al4 = (const float4*)(A_log + d * 16);
#pragma unroll
  for (int q = 0; q < 4; ++q) {
    float4 a = al4[q];
    Av[q * 4 + 0] = -__expf(a.x); Av[q * 4 + 1] = -__expf(a.y);
    Av[q * 4 + 2] = -__expf(a.z); Av[q * 4 + 3] = -__expf(a.w);
  }
  float Dp = D_param[d];
  float h[16];
  const float4* hi4 = (const float4*)(Hinit + (size_t)c * 32768 + d * 16);
#pragma unroll
  for (int q = 0; q < 4; ++q) {
    float4 v = hi4[q];
    h[q * 4 + 0] = v.x; h[q * 4 + 1] = v.y; h[q * 4 + 2] = v.z; h[q * 4 + 3] = v.w;
  }
#pragma unroll 2
  for (int i = 0; i < TCHUNK; ++i) {
    int t = t0 + i;
    float dtv = bf2f(dtb[(size_t)t * 2048 + d]);
    float xv = bf2f(x_ssm[(size_t)t * 2048 + d]);
    float dtx = dtv * xv;
    const float* B = x_dbl + t * 32;       // uniform
    const float* C = x_dbl + t * 32 + 16;  // uniform
    float y = 0.f;
#pragma unroll
    for (int s = 0; s < 16; ++s) {
      float dA = __expf(dtv * Av[s]);
      h[s] = fmaf(dA, h[s], B[s] * dtx);
      y = fmaf(h[s], C[s], y);
    }
    float szv = bf2f(silu_z[(size_t)t * 2048 + d]);
    y_out[(size_t)t * 2048 + d] = f2bf((y + Dp * xv) * szv);
  }
}

extern "C" void kernel_launch(void* const* d_in, const int* in_sizes, int n_in,
                              void* d_out, int out_size, void* d_ws, size_t ws_size,
                              hipStream_t stream) {
  const float* x      = (const float*)d_in[0];
  const float* W_in   = (const float*)d_in[1];
  const float* conv_w = (const float*)d_in[2];
  const float* conv_b = (const float*)d_in[3];
  const float* A_log  = (const float*)d_in[4];
  const float* D_par  = (const float*)d_in[5];
  const float* W_x    = (const float*)d_in[6];
  const float* W_dt   = (const float*)d_in[7];
  const float* b_dt   = (const float*)d_in[8];
  const float* W_out  = (const float*)d_in[9];
  float* out = (float*)d_out;

  char* ws = (char*)d_ws;
  unsigned short* xbf    = (unsigned short*)(ws + 0);                    // 4MB
  unsigned short* Winbf  = (unsigned short*)(ws + ((size_t)4 << 20));    // 8MB
  unsigned short* Wcomb  = (unsigned short*)(ws + ((size_t)12 << 20));   // 8.5MB [2176][2048]
  unsigned short* Woutbf = (unsigned short*)(ws + ((size_t)21 << 20));   // 4MB
  unsigned short* xz     = (unsigned short*)(ws + ((size_t)25 << 20));   // 16MB (free after conv)
  unsigned short* xssm   = (unsigned short*)(ws + ((size_t)41 << 20));   // 8MB (free after passC)
  unsigned short* siluz  = (unsigned short*)(ws + ((size_t)49 << 20));   // 8MB (free after passC)
  unsigned short* dtb    = (unsigned short*)(ws + ((size_t)57 << 20));   // 8MB (bf16 dt)
  float* xdbl            = (float*)(ws + ((size_t)65 << 20));            // 256KB
  unsigned short* yfin   = (unsigned short*)(ws + ((size_t)66 << 20));   // 8MB
  float* Pbuf            = (float*)(ws + ((size_t)25 << 20));            // 8MB (alias xz)
  float* Hloc            = (float*)(ws + ((size_t)4 << 20));             // 8MB (alias Winbf)
  float* part            = (float*)(ws + ((size_t)41 << 20));            // 16MB (alias xssm+siluz)

  // fp32 -> bf16 converts
  cvt_f32_bf16<<<2048, 256, 0, stream>>>((const float4*)x, (ushort4*)xbf, (L_SEQ * DMODEL) / 4);
  cvt_f32_bf16<<<4096, 256, 0, stream>>>((const float4*)W_in, (ushort4*)Winbf, (2 * DINNER * DMODEL) / 4);
  // Wcomb rows 0..2047 = W_dt, rows 2048..2079 = W_x, rows 2080..2175 = 0
  cvt_f32_bf16<<<4096, 256, 0, stream>>>((const float4*)W_dt, (ushort4*)Wcomb, (DINNER * DINNER) / 4);
  cvt_f32_bf16<<<64, 256, 0, stream>>>((const float4*)W_x, (ushort4*)(Wcomb + (size_t)2048 * 2048),
                                       (32 * DINNER) / 4);
  zero_bf16<<<192, 256, 0, stream>>>((ushort4*)(Wcomb + (size_t)2080 * 2048), (96 * DINNER) / 4);
  cvt_f32_bf16<<<2048, 256, 0, stream>>>((const float4*)W_out, (ushort4*)Woutbf, (DMODEL * DINNER) / 4);

  // GEMM1: xz[2048,4096] = x @ W_in^T  (bf16 out) — 512 blocks, K=1024 (16 stages)
  gemm_bk64<0><<<512, 256, 0, stream>>>(xbf, Winbf, L_SEQ, 4096, DMODEL, 32, 1,
                                        nullptr, xz, nullptr);

  // conv + silu -> x_ssm; silu(z)
  conv_silu8<<<2048, 256, 0, stream>>>(xz, conv_w, conv_b, xssm, siluz);

  // GEMM2 (fused): dt bf16 [2048,2048] (softplus) + x_dbl f32 [2048,32] — 272 blocks
  gemm_bk64<3><<<272, 256, 0, stream>>>(xssm, Wcomb, L_SEQ, 2176, DINNER, 17, 1,
                                        xdbl, dtb, b_dt);

  // chunked parallel scan
  scan_passA<<<NCHUNK * (DINNER / 256), 256, 0, stream>>>(dtb, xssm, xdbl, A_log, Pbuf, Hloc);
  scan_passB<<<(DINNER * 16) / 256, 256, 0, stream>>>(Pbuf, Hloc);
  scan_passC<<<NCHUNK * (DINNER / 256), 256, 0, stream>>>(dtb, xssm, xdbl, A_log, D_par, siluz,
                                                          Pbuf, yfin);

  // GEMM4: split-K x2 partials [2,2048,1024] f32 — 256 blocks, Ks=1024 (16 stages)
  gemm_bk64<4><<<256, 256, 0, stream>>>(yfin, Woutbf, L_SEQ, DMODEL, DINNER, 8, 2,
                                        part, nullptr, nullptr);
  // out = p0 + p1 + x
  reduce_addx<<<(L_SEQ * DMODEL / 4 + 255) / 256, 256, 0, stream>>>(
      (const float4*)part, (const float4*)x, (float4*)out, L_SEQ * DMODEL / 4);
}

// Round 8
// 277.005 us; speedup vs baseline: 1.3037x; 1.3037x over previous
//
#include <hip/hip_runtime.h>

#define L_SEQ 2048
#define DMODEL 1024
#define DINNER 2048
#define NCHUNK 64
#define TCHUNK 32

typedef __attribute__((ext_vector_type(8))) short bf16x8;
typedef __attribute__((ext_vector_type(4))) float f32x4;

__device__ __forceinline__ float bf2f(unsigned short u) {
  return __uint_as_float(((unsigned)u) << 16);
}
__device__ __forceinline__ unsigned short f2bf(float f) {
  unsigned u = __float_as_uint(f);
  return (unsigned short)((u + 0x7FFFu + ((u >> 16) & 1u)) >> 16);
}
__device__ __forceinline__ void gload_lds16(const void* g, void* l) {
  __builtin_amdgcn_global_load_lds(
      (const __attribute__((address_space(1))) void*)g,
      (__attribute__((address_space(3))) void*)l, 16, 0, 0);
}

// ---------------- fused fp32 -> bf16 converts (one kernel for all weights) ----------
__global__ __launch_bounds__(256) void cvt_all(
    const float4* __restrict__ x, const float4* __restrict__ Win,
    const float4* __restrict__ Wdt, const float4* __restrict__ Wx,
    const float4* __restrict__ Wout,
    ushort4* __restrict__ xbf, ushort4* __restrict__ winb, ushort4* __restrict__ wcomb,
    ushort4* __restrict__ wcombx, ushort4* __restrict__ woutb, ushort4* __restrict__ wcombz) {
  int i = blockIdx.x * 256 + threadIdx.x;
  const float4* s; ushort4* d; int j;
  if (i < 524288)        { s = x;    d = xbf;    j = i; }
  else if (i < 1572864)  { s = Win;  d = winb;   j = i - 524288; }
  else if (i < 2621440)  { s = Wdt;  d = wcomb;  j = i - 1572864; }
  else if (i < 2637824)  { s = Wx;   d = wcombx; j = i - 2621440; }
  else if (i < 3162112)  { s = Wout; d = woutb;  j = i - 2637824; }
  else                   { wcombz[i - 3162112] = ushort4{0, 0, 0, 0}; return; }
  float4 v = s[j];
  ushort4 o;
  o.x = f2bf(v.x); o.y = f2bf(v.y); o.z = f2bf(v.z); o.w = f2bf(v.w);
  d[j] = o;
}

// ---------------- bf16 GEMM, C = A[M,K] * B[N,K]^T ----------------
// 128x128 tile, BK=32, 3 LDS buffers, depth-2 counted vmcnt (T3+T4),
// source-side XOR swizzle (T2), XCD chunk swizzle (T1). ksplit in {1,2,4}.
// EPI: 0 = store bf16 at outb[row*N+col]
//      5 = bf16 partial at outb[ks*M*N + row*N + col]
template <int EPI>
__global__ __launch_bounds__(256) void gemm_bt3(
    const unsigned short* __restrict__ A, const unsigned short* __restrict__ B,
    int M, int N, int K, int nx, int ksplit,
    float* __restrict__ outf, unsigned short* __restrict__ outb,
    const float* __restrict__ aux) {
  __shared__ __align__(16) unsigned short As[3 * 128 * 32];
  __shared__ __align__(16) unsigned short Bs[3 * 128 * 32];
  const int tid = threadIdx.x;
  const int lane = tid & 63;
  const int wave = tid >> 6;
  const int wm = wave >> 1, wn = wave & 1;

  // XCD-aware bijective chunk swizzle (nwg % 8 == 0)
  const int nwg = gridDim.x;
  const int wg = blockIdx.x;
  const int swzb = (wg & 7) * (nwg >> 3) + (wg >> 3);
  const int tiles = nwg / ksplit;
  const int ks = swzb / tiles;
  const int t = swzb - ks * tiles;
  const int bx = t % nx, by = t / nx;
  const int bm = by * 128, bn = bx * 128;
  const int Ks = K / ksplit;
  const int kbeg = ks * Ks;
  const int nk = Ks >> 5;

  // staging: LDS dest linear (tid*16B); global source col-group XOR-permuted (T2 rule #21)
  const int srow = tid >> 2, sc4 = tid & 3;
  const int scp = sc4 ^ ((srow >> 1) & 3);
  const unsigned short* Ag = A + (size_t)(bm + srow) * K + scp * 8;
  const unsigned short* Bg = B + (size_t)(bn + srow) * K + scp * 8;
  unsigned short* AsW = &As[srow * 32 + sc4 * 8];
  unsigned short* BsW = &Bs[srow * 32 + sc4 * 8];

  auto STAGE = [&](int buf, int k0) {
    gload_lds16(Ag + k0, AsW + buf * 4096);
    gload_lds16(Ag + (size_t)64 * K + k0, AsW + buf * 4096 + 64 * 32);
    gload_lds16(Bg + k0, BsW + buf * 4096);
    gload_lds16(Bg + (size_t)64 * K + k0, BsW + buf * 4096 + 64 * 32);
  };

  f32x4 acc[4][4] = {};

  const int g = lane >> 4;
  const int r16 = lane & 15;
  const int sw = (g ^ ((r16 >> 1) & 3)) * 8;  // read-side of the same XOR

  STAGE(0, kbeg);
  STAGE(1, kbeg + 32);
  int cur = 0, stg = 2;

  for (int i = 0; i < nk; ++i) {
    if (i < nk - 1) {
      asm volatile("s_waitcnt vmcnt(4)" ::: "memory");
    } else {
      asm volatile("s_waitcnt vmcnt(0)" ::: "memory");
    }
    __builtin_amdgcn_s_barrier();
    asm volatile("" ::: "memory");
    if (i + 2 < nk) {
      STAGE(stg, kbeg + (i + 2) * 32);
      stg = (stg == 2) ? 0 : stg + 1;
    }

    bf16x8 a[4], b[4];
#pragma unroll
    for (int ii = 0; ii < 4; ++ii)
      a[ii] = *(const bf16x8*)&As[cur * 4096 + (wm * 64 + ii * 16 + r16) * 32 + sw];
#pragma unroll
    for (int j = 0; j < 4; ++j)
      b[j] = *(const bf16x8*)&Bs[cur * 4096 + (wn * 64 + j * 16 + r16) * 32 + sw];
#pragma unroll
    for (int ii = 0; ii < 4; ++ii)
#pragma unroll
      for (int j = 0; j < 4; ++j)
        acc[ii][j] = __builtin_amdgcn_mfma_f32_16x16x32_bf16(a[ii], b[j], acc[ii][j], 0, 0, 0);

    cur = (cur == 2) ? 0 : cur + 1;
  }

  const int rq = lane >> 4;
#pragma unroll
  for (int i = 0; i < 4; ++i)
#pragma unroll
    for (int j = 0; j < 4; ++j)
#pragma unroll
      for (int r = 0; r < 4; ++r) {
        int row = bm + wm * 64 + i * 16 + rq * 4 + r;
        int col = bn + wn * 64 + j * 16 + r16;
        float v = acc[i][j][r];
        if (EPI == 0) {
          outb[(size_t)row * N + col] = f2bf(v);
        } else {  // EPI == 5: bf16 split-K partial
          outb[(size_t)ks * M * N + (size_t)row * N + col] = f2bf(v);
        }
      }
}

// ---------------- GEMM2 split-K reduce: softplus(dt)+b_dt -> bf16; extract x_dbl ------
__global__ __launch_bounds__(256) void g2reduce(
    const unsigned short* __restrict__ p, const float* __restrict__ bdt,
    unsigned short* __restrict__ dtb, float* __restrict__ xdbl) {
  int b = blockIdx.x;
  if (b < 2048) {
    int c0 = threadIdx.x * 8;
    size_t o0 = (size_t)b * 2176 + c0;
    bf16x8 v0 = *(const bf16x8*)(p + o0);
    bf16x8 v1 = *(const bf16x8*)(p + (size_t)2048 * 2176 + o0);
    float4 ba = *(const float4*)(bdt + c0);
    float4 bb = *(const float4*)(bdt + c0 + 4);
    float bv[8] = {ba.x, ba.y, ba.z, ba.w, bb.x, bb.y, bb.z, bb.w};
    bf16x8 o;
#pragma unroll
    for (int j = 0; j < 8; ++j) {
      float t = bf2f((unsigned short)v0[j]) + bf2f((unsigned short)v1[j]) + bv[j];
      float sp = (t > 15.f) ? t : log1pf(__expf(t));
      o[j] = (short)f2bf(sp);
    }
    *(bf16x8*)(dtb + (size_t)b * 2048 + c0) = o;
  } else {
    int idx = (b - 2048) * 256 + threadIdx.x;  // 16384 = 2048 rows * 8
    int row = idx >> 3, c4 = (idx & 7) * 4;
    size_t o0 = (size_t)row * 2176 + 2048 + c4;
    float4 r;
    r.x = bf2f(p[o0 + 0]) + bf2f(p[(size_t)2048 * 2176 + o0 + 0]);
    r.y = bf2f(p[o0 + 1]) + bf2f(p[(size_t)2048 * 2176 + o0 + 1]);
    r.z = bf2f(p[o0 + 2]) + bf2f(p[(size_t)2048 * 2176 + o0 + 2]);
    r.w = bf2f(p[o0 + 3]) + bf2f(p[(size_t)2048 * 2176 + o0 + 3]);
    *(float4*)(xdbl + row * 32 + c4) = r;
  }
}

// ---------------- GEMM4 split-K(4) reduce + residual add ----------------
__global__ __launch_bounds__(256) void addx4(
    const unsigned short* __restrict__ p, const float* __restrict__ x,
    float* __restrict__ out) {
  int i = blockIdx.x * 256 + threadIdx.x;  // 262144 groups of 8
  size_t base = (size_t)i * 8;
  bf16x8 a0 = *(const bf16x8*)(p + base);
  bf16x8 a1 = *(const bf16x8*)(p + 2097152 + base);
  bf16x8 a2 = *(const bf16x8*)(p + 4194304 + base);
  bf16x8 a3 = *(const bf16x8*)(p + 6291456 + base);
  float4 x0 = *(const float4*)(x + base);
  float4 x1 = *(const float4*)(x + base + 4);
  float xs[8] = {x0.x, x0.y, x0.z, x0.w, x1.x, x1.y, x1.z, x1.w};
  float4 o0, o1;
#pragma unroll
  for (int j = 0; j < 8; ++j) {
    float v = bf2f((unsigned short)a0[j]) + bf2f((unsigned short)a1[j]) +
              bf2f((unsigned short)a2[j]) + bf2f((unsigned short)a3[j]) + xs[j];
    if (j < 4) ((float*)&o0)[j] = v; else ((float*)&o1)[j - 4] = v;
  }
  *(float4*)(out + base) = o0;
  *(float4*)(out + base + 4) = o1;
}

// ---------------- causal depthwise conv (D_CONV=4) + SiLU; also silu(z) ----------------
__global__ __launch_bounds__(256) void conv_silu8(
    const unsigned short* __restrict__ xz,
    const float* __restrict__ cw, const float* __restrict__ cb,
    unsigned short* __restrict__ x_ssm, unsigned short* __restrict__ sz_out) {
  int idx = blockIdx.x * 256 + threadIdx.x;  // 2048 l * 256 cgroups
  int l = idx >> 8, c0 = (idx & 255) * 8;
  float acc[8];
  float4 b0 = *(const float4*)(cb + c0);
  float4 b1 = *(const float4*)(cb + c0 + 4);
  acc[0] = b0.x; acc[1] = b0.y; acc[2] = b0.z; acc[3] = b0.w;
  acc[4] = b1.x; acc[5] = b1.y; acc[6] = b1.z; acc[7] = b1.w;
  float4 w[8];
#pragma unroll
  for (int j = 0; j < 8; ++j) w[j] = *(const float4*)(cw + (c0 + j) * 4);
#pragma unroll
  for (int k = 0; k < 4; ++k) {
    int lt = l - 3 + k;
    if (lt >= 0) {
      bf16x8 v = *(const bf16x8*)(xz + (size_t)lt * 4096 + c0);
      const float* wk = (const float*)w;
#pragma unroll
      for (int j = 0; j < 8; ++j)
        acc[j] = fmaf(bf2f((unsigned short)v[j]), wk[j * 4 + k], acc[j]);
    }
  }
  bf16x8 zr = *(const bf16x8*)(xz + (size_t)l * 4096 + 2048 + c0);
  bf16x8 ox, oz;
#pragma unroll
  for (int j = 0; j < 8; ++j) {
    float a = acc[j];
    ox[j] = (short)f2bf(a / (1.f + __expf(-a)));
    float zv = bf2f((unsigned short)zr[j]);
    oz[j] = (short)f2bf(zv / (1.f + __expf(-zv)));
  }
  *(bf16x8*)(x_ssm + (size_t)idx * 8) = ox;
  *(bf16x8*)(sz_out + (size_t)idx * 8) = oz;
}

// ---------------- chunked parallel scan, thread-per-channel (16 states in regs) ----------
__global__ __launch_bounds__(256) void scan_passA(
    const unsigned short* __restrict__ dtb, const unsigned short* __restrict__ x_ssm,
    const float* __restrict__ x_dbl, const float* __restrict__ A_log,
    float* __restrict__ Pout, float* __restrict__ Hout) {
  int tid = threadIdx.x;
  int c = blockIdx.x & (NCHUNK - 1), db = blockIdx.x / NCHUNK;
  int d = db * 256 + tid;
  int t0 = c * TCHUNK;
  float Av[16];
  const float4* al4 = (const float4*)(A_log + d * 16);
#pragma unroll
  for (int q = 0; q < 4; ++q) {
    float4 a = al4[q];
    Av[q * 4 + 0] = -__expf(a.x); Av[q * 4 + 1] = -__expf(a.y);
    Av[q * 4 + 2] = -__expf(a.z); Av[q * 4 + 3] = -__expf(a.w);
  }
  float h[16];
#pragma unroll
  for (int s = 0; s < 16; ++s) h[s] = 0.f;
  float sum_dt = 0.f;
#pragma unroll 2
  for (int i = 0; i < TCHUNK; ++i) {
    int t = t0 + i;
    float dtv = bf2f(dtb[(size_t)t * 2048 + d]);
    float xv = bf2f(x_ssm[(size_t)t * 2048 + d]);
    float dtx = dtv * xv;
    sum_dt += dtv;
    const float* B = x_dbl + t * 32;  // wave-uniform -> scalar loads
#pragma unroll
    for (int s = 0; s < 16; ++s) {
      float dA = __expf(dtv * Av[s]);
      h[s] = fmaf(dA, h[s], B[s] * dtx);
    }
  }
  float* Ho = Hout + (size_t)c * 32768 + d * 16;
  float* Po = Pout + (size_t)c * 32768 + d * 16;
#pragma unroll
  for (int s = 0; s < 16; ++s) Ho[s] = h[s];
#pragma unroll
  for (int s = 0; s < 16; ++s) Po[s] = __expf(sum_dt * Av[s]);
}

// Pass B: serial combine; rewrites P buffer in-place with chunk-entry states (Hinit).
__global__ __launch_bounds__(256) void scan_passB(
    float* __restrict__ P, const float* __restrict__ Hloc) {
  int i = blockIdx.x * 256 + threadIdx.x;  // 32768 (d,s)
  float h = 0.f;
#pragma unroll 8
  for (int c = 0; c < NCHUNK; ++c) {
    size_t o = (size_t)c * 32768 + i;
    float p = P[o];
    float hl = Hloc[o];
    P[o] = h;
    h = fmaf(p, h, hl);
  }
}

// Pass C: re-run chunk from entry state; emit gated y (bf16).
__global__ __launch_bounds__(256) void scan_passC(
    const unsigned short* __restrict__ dtb, const unsigned short* __restrict__ x_ssm,
    const float* __restrict__ x_dbl, const float* __restrict__ A_log,
    const float* __restrict__ D_param, const unsigned short* __restrict__ silu_z,
    const float* __restrict__ Hinit, unsigned short* __restrict__ y_out) {
  int tid = threadIdx.x;
  int c = blockIdx.x & (NCHUNK - 1), db = blockIdx.x / NCHUNK;
  int d = db * 256 + tid;
  int t0 = c * TCHUNK;
  float Av[16];
  const float4* al4 = (const float4*)(A_log + d * 16);
#pragma unroll
  for (int q = 0; q < 4; ++q) {
    float4 a = al4[q];
    Av[q * 4 + 0] = -__expf(a.x); Av[q * 4 + 1] = -__expf(a.y);
    Av[q * 4 + 2] = -__expf(a.z); Av[q * 4 + 3] = -__expf(a.w);
  }
  float Dp = D_param[d];
  float h[16];
  const float4* hi4 = (const float4*)(Hinit + (size_t)c * 32768 + d * 16);
#pragma unroll
  for (int q = 0; q < 4; ++q) {
    float4 v = hi4[q];
    h[q * 4 + 0] = v.x; h[q * 4 + 1] = v.y; h[q * 4 + 2] = v.z; h[q * 4 + 3] = v.w;
  }
#pragma unroll 2
  for (int i = 0; i < TCHUNK; ++i) {
    int t = t0 + i;
    float dtv = bf2f(dtb[(size_t)t * 2048 + d]);
    float xv = bf2f(x_ssm[(size_t)t * 2048 + d]);
    float dtx = dtv * xv;
    const float* B = x_dbl + t * 32;       // uniform
    const float* C = x_dbl + t * 32 + 16;  // uniform
    float y = 0.f;
#pragma unroll
    for (int s = 0; s < 16; ++s) {
      float dA = __expf(dtv * Av[s]);
      h[s] = fmaf(dA, h[s], B[s] * dtx);
      y = fmaf(h[s], C[s], y);
    }
    float szv = bf2f(silu_z[(size_t)t * 2048 + d]);
    y_out[(size_t)t * 2048 + d] = f2bf((y + Dp * xv) * szv);
  }
}

extern "C" void kernel_launch(void* const* d_in, const int* in_sizes, int n_in,
                              void* d_out, int out_size, void* d_ws, size_t ws_size,
                              hipStream_t stream) {
  const float* x      = (const float*)d_in[0];
  const float* W_in   = (const float*)d_in[1];
  const float* conv_w = (const float*)d_in[2];
  const float* conv_b = (const float*)d_in[3];
  const float* A_log  = (const float*)d_in[4];
  const float* D_par  = (const float*)d_in[5];
  const float* W_x    = (const float*)d_in[6];
  const float* W_dt   = (const float*)d_in[7];
  const float* b_dt   = (const float*)d_in[8];
  const float* W_out  = (const float*)d_in[9];
  float* out = (float*)d_out;

  // Workspace layout (MB offsets; lifetime-disjoint aliases noted). Peak 74 MB.
  char* ws = (char*)d_ws;
  unsigned short* xbf    = (unsigned short*)(ws + 0);                    // [cvt->G1]
  unsigned short* Winbf  = (unsigned short*)(ws + ((size_t)4 << 20));    // [cvt->G1]
  unsigned short* Wcomb  = (unsigned short*)(ws + ((size_t)12 << 20));   // 8.5MB [cvt->G2]
  float* xdbl            = (float*)(ws + ((size_t)41 << 19));            // 20.5MB [g2red->passC]
  unsigned short* Woutbf = (unsigned short*)(ws + ((size_t)21 << 20));   // [cvt->G4]
  unsigned short* xz     = (unsigned short*)(ws + ((size_t)25 << 20));   // 16MB [G1->conv]
  unsigned short* part2  = (unsigned short*)(ws + ((size_t)25 << 20));   // 17MB [G2->g2red]
  unsigned short* yfin   = (unsigned short*)(ws + ((size_t)25 << 20));   // 8MB [passC->G4]
  unsigned short* part4  = (unsigned short*)(ws + ((size_t)33 << 20));   // 16MB [G4->addx4]
  unsigned short* xssm   = (unsigned short*)(ws + ((size_t)50 << 20));   // 8MB [conv->passC]
  unsigned short* siluz  = (unsigned short*)(ws + ((size_t)58 << 20));   // 8MB [conv->passC]
  unsigned short* dtb    = (unsigned short*)(ws + ((size_t)66 << 20));   // 8MB [g2red->passC]
  float* Pbuf            = (float*)(ws + 0);                             // 8MB [passA->passC]
  float* Hloc            = (float*)(ws + ((size_t)12 << 20));            // 8MB [passA->passB]

  // one fused convert kernel: x, W_in, W_dt->Wcomb[0:2048], W_x->Wcomb[2048:2080],
  // W_out, zeros->Wcomb[2080:2176]
  cvt_all<<<12544, 256, 0, stream>>>(
      (const float4*)x, (const float4*)W_in, (const float4*)W_dt, (const float4*)W_x,
      (const float4*)W_out,
      (ushort4*)xbf, (ushort4*)Winbf, (ushort4*)Wcomb,
      (ushort4*)(Wcomb + (size_t)2048 * 2048), (ushort4*)Woutbf,
      (ushort4*)(Wcomb + (size_t)2080 * 2048));

  // GEMM1: xz[2048,4096] = x @ W_in^T (bf16) — 512 blocks, 2/CU
  gemm_bt3<0><<<512, 256, 0, stream>>>(xbf, Winbf, L_SEQ, 4096, DMODEL, 32, 1,
                                       nullptr, xz, nullptr);

  // conv + silu -> x_ssm; silu(z)
  conv_silu8<<<2048, 256, 0, stream>>>(xz, conv_w, conv_b, xssm, siluz);

  // GEMM2: split-K x2 bf16 partials [2,2048,2176] — 544 blocks, 2.1/CU
  gemm_bt3<5><<<544, 256, 0, stream>>>(xssm, Wcomb, L_SEQ, 2176, DINNER, 17, 2,
                                       nullptr, part2, nullptr);
  // reduce: dt = softplus(p0+p1+b_dt) -> bf16; x_dbl = p0+p1 (cols 2048..2079)
  g2reduce<<<2048 + 64, 256, 0, stream>>>(part2, b_dt, dtb, xdbl);

  // chunked parallel scan
  scan_passA<<<NCHUNK * (DINNER / 256), 256, 0, stream>>>(dtb, xssm, xdbl, A_log, Pbuf, Hloc);
  scan_passB<<<(DINNER * 16) / 256, 256, 0, stream>>>(Pbuf, Hloc);
  scan_passC<<<NCHUNK * (DINNER / 256), 256, 0, stream>>>(dtb, xssm, xdbl, A_log, D_par, siluz,
                                                          Pbuf, yfin);

  // GEMM4: split-K x4 bf16 partials [4,2048,1024] — 512 blocks, 2/CU
  gemm_bt3<5><<<512, 256, 0, stream>>>(yfin, Woutbf, L_SEQ, DMODEL, DINNER, 8, 4,
                                       nullptr, part4, nullptr);
  // out = p0+p1+p2+p3 + x
  addx4<<<1024, 256, 0, stream>>>(part4, x, out);
}